// Round 5
// baseline (605.386 us; speedup 1.0000x reference)
//
#include <hip/hip_runtime.h>

typedef unsigned short ushort_t;
typedef float f32x4 __attribute__((ext_vector_type(4)));
typedef _Float16 f16x8 __attribute__((ext_vector_type(8)));
typedef _Float16 f16x4 __attribute__((ext_vector_type(4)));

#define NB 256
#define NL 256
#define NIN 256
#define ND 128
#define NH 64
#define BL (NB * NL)                 // 65536 rows
#define BLD ((size_t)BL * ND)        // 8,388,608 elements per gate
#define CH 16                        // X-staging chunk (steps)

// raw barrier: LDS-only drain (no vmcnt!) — global stores/loads float free
#define BAR_LDS() asm volatile("s_waitcnt lgkmcnt(0)\n\ts_barrier" ::: "memory")
#define WAIT_VM0() asm volatile("s_waitcnt vmcnt(0)" ::: "memory")

__device__ __forceinline__ void gload_lds16(const _Float16* gp, _Float16* lp) {
  __builtin_amdgcn_global_load_lds(
      (const __attribute__((address_space(1))) void*)gp,
      (__attribute__((address_space(3))) void*)lp, 16, 0, 0);
}

// =====================================================================
// Kernel A v2: a[b,t] = sigmoid(x[b,t,:] . (k1 - k2)), coalesced.
// 16 lanes per row: lane reads contiguous float4s; shfl_xor reduce.
// =====================================================================
__global__ void ka_kernel(const float* __restrict__ x,
                          const float* __restrict__ k1k2,
                          float* __restrict__ wsA) {
  const int tid = threadIdx.x;
  const int c16 = tid & 15;            // col group within row
  const int row = blockIdx.x * 16 + (tid >> 4);
  const float4* xp = (const float4*)(x + (size_t)row * NIN);
  const float4* k1 = (const float4*)(k1k2);
  const float4* k2 = (const float4*)(k1k2 + NIN);
  float acc = 0.f;
#pragma unroll
  for (int i = 0; i < 4; ++i) {
    int col = c16 + 16 * i;            // float4 index; lanes contiguous
    float4 xv = xp[col];
    float4 a1 = k1[col];
    float4 a2 = k2[col];
    acc += xv.x * (a1.x - a2.x) + xv.y * (a1.y - a2.y) +
           xv.z * (a1.z - a2.z) + xv.w * (a1.w - a2.w);
  }
  acc += __shfl_xor(acc, 1);
  acc += __shfl_xor(acc, 2);
  acc += __shfl_xor(acc, 4);
  acc += __shfl_xor(acc, 8);
  if (c16 == 0) wsA[row] = 1.f / (1.f + __expf(-acc));
}

// =====================================================================
// Kernel B: X_g = x @ w_g^T, single-term f16 MFMA (unchanged this round)
// =====================================================================
__global__ __launch_bounds__(256, 2) void kproj_kernel(
    const float* __restrict__ x, const float* __restrict__ w_r,
    const float* __restrict__ w_z, const float* __restrict__ w_h,
    _Float16* __restrict__ wsX) {
  const int g = blockIdx.y;
  const float* w = (g == 0) ? w_r : (g == 1) ? w_z : w_h;
  const int r0 = blockIdx.x * 128;

  __shared__ __align__(16) _Float16 Ah[128 * 40];
  __shared__ __align__(16) _Float16 Bh[128 * 40];

  const int tid = threadIdx.x;
  const int lane = tid & 63;
  const int wv = tid >> 6;
  const int wrow = (wv >> 1) * 64;
  const int wcol = (wv & 1) * 64;
  const int fr = lane & 15;
  const int fg = lane >> 4;

  f32x4 acc[4][4];
#pragma unroll
  for (int m = 0; m < 4; ++m)
#pragma unroll
    for (int n = 0; n < 4; ++n) acc[m][n] = (f32x4){0.f, 0.f, 0.f, 0.f};

  const int srow = tid >> 1;
  const int kseg = (tid & 1) * 16;

  for (int kc = 0; kc < 8; ++kc) {
    const int k0 = kc * 32;
    const float4* xp = (const float4*)(x + (size_t)(r0 + srow) * NIN + k0 + kseg);
    const float4* wp = (const float4*)(w + (size_t)srow * NIN + k0 + kseg);
#pragma unroll
    for (int i = 0; i < 4; ++i) {
      float4 xv = xp[i];
      float4 wvv = wp[i];
      int base = srow * 40 + kseg + 4 * i;
      f16x4 av, bv;
      av[0] = (_Float16)xv.x;  av[1] = (_Float16)xv.y;
      av[2] = (_Float16)xv.z;  av[3] = (_Float16)xv.w;
      bv[0] = (_Float16)wvv.x; bv[1] = (_Float16)wvv.y;
      bv[2] = (_Float16)wvv.z; bv[3] = (_Float16)wvv.w;
      *(f16x4*)(&Ah[base]) = av;
      *(f16x4*)(&Bh[base]) = bv;
    }
    __syncthreads();

    f16x8 a4[4], b4[4];
#pragma unroll
    for (int m = 0; m < 4; ++m) {
      a4[m] = *(const f16x8*)(&Ah[(wrow + m * 16 + fr) * 40 + 8 * fg]);
      b4[m] = *(const f16x8*)(&Bh[(wcol + m * 16 + fr) * 40 + 8 * fg]);
    }
#pragma unroll
    for (int m = 0; m < 4; ++m)
#pragma unroll
      for (int n = 0; n < 4; ++n)
        acc[m][n] = __builtin_amdgcn_mfma_f32_16x16x32_f16(a4[m], b4[n], acc[m][n], 0, 0, 0);
    __syncthreads();
  }

#pragma unroll
  for (int m = 0; m < 4; ++m)
#pragma unroll
    for (int n = 0; n < 4; ++n)
#pragma unroll
      for (int r = 0; r < 4; ++r) {
        int row = r0 + wrow + m * 16 + fg * 4 + r;
        int col = wcol + n * 16 + fr;
        wsX[(size_t)g * BLD + (size_t)row * ND + col] = (_Float16)acc[m][n][r];
      }
}

// =====================================================================
// Kernel C v5: 2-wave MFMA scan. 256 blocks x 128 threads.
// Wave w owns d in [64w, 64w+64): 4 n-tiles x 3 gates, K lo/hi split.
// Barrier syncs only 2 waves; wave0 writes hprev16, wave1 writes hist.
// =====================================================================
__global__ __launch_bounds__(128, 1) void kscan_kernel(
    const float* __restrict__ u_r, const float* __restrict__ u_z,
    const float* __restrict__ u_h, const float* __restrict__ b_r,
    const float* __restrict__ b_z, const float* __restrict__ b_h,
    const int* __restrict__ cor, const _Float16* __restrict__ wsX,
    const float* __restrict__ wsA, float* __restrict__ out) {
  const int b = blockIdx.x;
  const int tid = threadIdx.x;
  const int lane = tid & 63;
  const int w = tid >> 6;        // wave id (0/1) -> d range [64w, 64w+64)
  const int quad = lane >> 4;
  const int l16 = lane & 15;
  const int q8 = quad * 8;

  __shared__ __align__(16) _Float16 hist[(NL + 1) * NH];   // 32896 B
  __shared__ __align__(16) _Float16 Xl[2 * 3 * CH * ND];   // 24576 B
  __shared__ __align__(16) float hprev32[2][ND];           // 1024 B (parity)
  __shared__ __align__(16) _Float16 hprev16[2][NH];        // 256 B (parity)
  __shared__ float sA[NL];
  __shared__ int sCor[NL];

  // ---- B fragments: u_g[n][k] f16; n = 64w+16tt+l16, k = kk*32+q8+j ----
  f16x8 bf[3][4][4];
#pragma unroll
  for (int g = 0; g < 3; ++g) {
    const float* ug = (g == 0) ? u_r : (g == 1) ? u_z : u_h;
#pragma unroll
    for (int tt = 0; tt < 4; ++tt) {
      const float* base = ug + (size_t)(64 * w + 16 * tt + l16) * ND;
#pragma unroll
      for (int kk = 0; kk < 4; ++kk) {
        const float4* p = (const float4*)(base + kk * 32 + q8);
        float4 v0 = p[0], v1 = p[1];
        f16x8 f;
        f[0] = (_Float16)v0.x; f[1] = (_Float16)v0.y;
        f[2] = (_Float16)v0.z; f[3] = (_Float16)v0.w;
        f[4] = (_Float16)v1.x; f[5] = (_Float16)v1.y;
        f[6] = (_Float16)v1.z; f[7] = (_Float16)v1.w;
        bf[g][tt][kk] = f;
      }
    }
  }

  const size_t rowb = (size_t)b * NL;
  hprev32[0][tid] = 0.f;
  if (tid < NH) { hprev16[0][tid] = (_Float16)0.f; hist[tid] = (_Float16)0.f; }
  sA[tid] = wsA[rowb + tid];
  sA[tid + 128] = wsA[rowb + tid + 128];
  sCor[tid] = cor[rowb + tid];
  sCor[tid + 128] = cor[rowb + tid + 128];

  // ---- chunk 0 of X into Xl buf 0 (12 x 1KB segments, 6 per wave) ----
  {
    const _Float16* srcb = wsX + rowb * ND + lane * 8;
#pragma unroll
    for (int i = 0; i < 6; ++i) {
      int s = 6 * w + i;                  // segment 0..11
      int g = s >> 2, part = s & 3;
      gload_lds16(srcb + (size_t)g * BLD + part * 512,
                  &Xl[g * (CH * ND) + part * 512 + lane * 8]);
    }
  }

  const bool owner = (quad == 0);
  float bb[3][4];
  if (owner) {
#pragma unroll
    for (int tt = 0; tt < 4; ++tt) {
      int d = 64 * w + 16 * tt + l16;
      bb[0][tt] = b_r[d]; bb[1][tt] = b_z[d]; bb[2][tt] = b_h[d];
    }
  }
  __syncthreads();   // full drain once: chunk-0 loads + LDS init visible

  // ---- pipelined per-step state ----
  float a_c = sA[0];
  int c0 = sCor[0];
  int ieff_c = (c0 == 0) ? 0 : c0;
  bool pf_c = true;
  f16x8 af2 = *(const f16x8*)&hist[ieff_c * NH + q8];
  f16x8 af3 = *(const f16x8*)&hist[ieff_c * NH + 32 + q8];

  for (int t = 0; t < NL; ++t) {
    const int par = t & 1;
    const float a = a_c;
    const float oma = 1.f - a;
    const int ieff = ieff_c;
    const int cur = (t >> 4) & 1;
    const int tin = t & 15;

    // ---- issue next X chunk (once per 16 steps) ----
    if ((t & 15) == 0 && t + CH < NL) {
      const _Float16* srcb = wsX + (rowb + t + CH) * ND + lane * 8;
      _Float16* dstb = &Xl[(cur ^ 1) * (3 * CH * ND)];
#pragma unroll
      for (int i = 0; i < 6; ++i) {
        int s = 6 * w + i;
        int g = s >> 2, part = s & 3;
        gload_lds16(srcb + (size_t)g * BLD + part * 512,
                    dstb + g * (CH * ND) + part * 512 + lane * 8);
      }
    }

    // ---- hist frags: prefetched last step unless row was written last step
    if (!pf_c) {
      af2 = *(const f16x8*)&hist[ieff * NH + q8];
      af3 = *(const f16x8*)&hist[ieff * NH + 32 + q8];
    }
    f16x8 af0 = *(const f16x8*)&hprev16[par][q8];
    f16x8 af1 = *(const f16x8*)&hprev16[par][32 + q8];

    // ---- X + md reads for this step (owner lanes; from LDS) ----
    float xv[3][4], md[4];
    if (owner) {
      const _Float16* xp = &Xl[cur * (3 * CH * ND) + tin * ND];
#pragma unroll
      for (int tt = 0; tt < 4; ++tt) {
        int d = 64 * w + 16 * tt + l16;
        xv[0][tt] = (float)xp[d];
        xv[1][tt] = (float)xp[CH * ND + d];
        xv[2][tt] = (float)xp[2 * CH * ND + d];
        if (w == 0) {
          md[tt] = a * hprev32[par][d];
        } else if (ieff == t) {
          md[tt] = oma * hprev32[par][d];
        } else {
          md[tt] = oma * (float)hist[ieff * NH + (d - NH)];
        }
      }
    }

    // ---- MFMA: lo (k<64) and hi (k>=64) accumulators ----
    f32x4 accL[3][4], accH[3][4];
#pragma unroll
    for (int g = 0; g < 3; ++g)
#pragma unroll
      for (int tt = 0; tt < 4; ++tt) {
        accL[g][tt] = (f32x4){0.f, 0.f, 0.f, 0.f};
        accH[g][tt] = (f32x4){0.f, 0.f, 0.f, 0.f};
      }
#pragma unroll
    for (int g = 0; g < 3; ++g)
#pragma unroll
      for (int tt = 0; tt < 4; ++tt) {
        accL[g][tt] = __builtin_amdgcn_mfma_f32_16x16x32_f16(af0, bf[g][tt][0], accL[g][tt], 0, 0, 0);
        accH[g][tt] = __builtin_amdgcn_mfma_f32_16x16x32_f16(af2, bf[g][tt][2], accH[g][tt], 0, 0, 0);
        accL[g][tt] = __builtin_amdgcn_mfma_f32_16x16x32_f16(af1, bf[g][tt][1], accL[g][tt], 0, 0, 0);
        accH[g][tt] = __builtin_amdgcn_mfma_f32_16x16x32_f16(af3, bf[g][tt][3], accH[g][tt], 0, 0, 0);
      }

    // ---- prefetch step-(t+1) state (overlaps MFMA/epilogue) ----
    const int tn = (t < NL - 1) ? t + 1 : t;
    float a_n = sA[tn];
    int c_n = sCor[tn];
    int ieff_n = (c_n == 0) ? tn : c_n;
    bool pf_n = (ieff_n <= t);         // row stable during this step?
    f16x8 af2n, af3n;
    if (pf_n) {
      af2n = *(const f16x8*)&hist[ieff_n * NH + q8];
      af3n = *(const f16x8*)&hist[ieff_n * NH + 32 + q8];
    }

    // ---- epilogue (owner lanes; row 0 of C => quad 0, reg 0) ----
    if (owner) {
#pragma unroll
      for (int tt = 0; tt < 4; ++tt) {
        float dr = a * accL[0][tt][0] + oma * accH[0][tt][0];
        float dz = a * accL[1][tt][0] + oma * accH[1][tt][0];
        float dh = a * accL[2][tt][0] + oma * accH[2][tt][0];
        float rr = 1.f / (1.f + __expf(-(xv[0][tt] + bb[0][tt] + dr)));
        float zz = 1.f / (1.f + __expf(-(xv[1][tt] + bb[1][tt] + dz)));
        float e2 = __expf(2.f * (xv[2][tt] + bb[2][tt] + rr * dh));
        float hh = (e2 - 1.f) / (e2 + 1.f);
        float h = (1.f - zz) * md[tt] + zz * hh;
        int d = 64 * w + 16 * tt + l16;
        out[(rowb + t) * ND + d] = h;      // never drained per-step
        hprev32[par ^ 1][d] = h;
        if (w == 0) hprev16[par ^ 1][d] = (_Float16)h;
        else        hist[(t + 1) * NH + (d - NH)] = (_Float16)h;
      }
    }

    // ---- barrier: LDS drain only; vmcnt(0) only at chunk boundaries ----
    if ((t & 15) == 15) WAIT_VM0();
    BAR_LDS();

    a_c = a_n; ieff_c = ieff_n; pf_c = pf_n;
    if (pf_n) { af2 = af2n; af3 = af3n; }
  }
}

// =====================================================================
extern "C" void kernel_launch(void* const* d_in, const int* in_sizes, int n_in,
                              void* d_out, int out_size, void* d_ws, size_t ws_size,
                              hipStream_t stream) {
  (void)in_sizes; (void)n_in; (void)out_size; (void)ws_size;
  const float* x    = (const float*)d_in[0];
  const int*   cor  = (const int*)d_in[1];
  const float* w_r  = (const float*)d_in[2];
  const float* b_r  = (const float*)d_in[3];
  const float* u_r  = (const float*)d_in[4];
  const float* w_z  = (const float*)d_in[5];
  const float* b_z  = (const float*)d_in[6];
  const float* u_z  = (const float*)d_in[7];
  const float* w_h  = (const float*)d_in[8];
  const float* b_h  = (const float*)d_in[9];
  const float* u_h  = (const float*)d_in[10];
  const float* k1k2 = (const float*)d_in[11];

  _Float16* wsX = (_Float16*)d_ws;                       // 3*BL*ND f16 = 48 MB
  float* wsA = (float*)((char*)d_ws + 3 * BLD * 2);      // BL f32 = 256 KB

  ka_kernel<<<dim3(BL / 16), dim3(256), 0, stream>>>(x, k1k2, wsA);
  kproj_kernel<<<dim3(BL / 128, 3), dim3(256), 0, stream>>>(x, w_r, w_z, w_h, wsX);
  kscan_kernel<<<dim3(NB), dim3(128), 0, stream>>>(u_r, u_z, u_h, b_r, b_z, b_h,
                                                   cor, wsX, wsA, (float*)d_out);
}

// Round 6
// 383.056 us; speedup vs baseline: 1.5804x; 1.5804x over previous
//
#include <hip/hip_runtime.h>

typedef unsigned short ushort_t;
typedef float f32x4 __attribute__((ext_vector_type(4)));
typedef _Float16 f16x8 __attribute__((ext_vector_type(8)));
typedef _Float16 f16x4 __attribute__((ext_vector_type(4)));

#define NB 256
#define NL 256
#define NIN 256
#define ND 128
#define NH 64
#define BL (NB * NL)                 // 65536 rows
#define BLD ((size_t)BL * ND)        // 8,388,608 elements per gate
#define CH 16                        // X-staging chunk (steps)

// raw barrier: LDS-only drain (no vmcnt!) — global ops float across it
#define BAR_LDS() asm volatile("s_waitcnt lgkmcnt(0)\n\ts_barrier" ::: "memory")
#define WAIT_VM0() asm volatile("s_waitcnt vmcnt(0)" ::: "memory")

__device__ __forceinline__ void gload_lds16(const _Float16* gp, _Float16* lp) {
  __builtin_amdgcn_global_load_lds(
      (const __attribute__((address_space(1))) void*)gp,
      (__attribute__((address_space(3))) void*)lp, 16, 0, 0);
}

// =====================================================================
// Kernel A v2: a[b,t] = sigmoid(x[b,t,:] . (k1 - k2)), coalesced.
// =====================================================================
__global__ void ka_kernel(const float* __restrict__ x,
                          const float* __restrict__ k1k2,
                          float* __restrict__ wsA) {
  const int tid = threadIdx.x;
  const int c16 = tid & 15;
  const int row = blockIdx.x * 16 + (tid >> 4);
  const float4* xp = (const float4*)(x + (size_t)row * NIN);
  const float4* k1 = (const float4*)(k1k2);
  const float4* k2 = (const float4*)(k1k2 + NIN);
  float acc = 0.f;
#pragma unroll
  for (int i = 0; i < 4; ++i) {
    int col = c16 + 16 * i;
    float4 xv = xp[col];
    float4 a1 = k1[col];
    float4 a2 = k2[col];
    acc += xv.x * (a1.x - a2.x) + xv.y * (a1.y - a2.y) +
           xv.z * (a1.z - a2.z) + xv.w * (a1.w - a2.w);
  }
  acc += __shfl_xor(acc, 1);
  acc += __shfl_xor(acc, 2);
  acc += __shfl_xor(acc, 4);
  acc += __shfl_xor(acc, 8);
  if (c16 == 0) wsA[row] = 1.f / (1.f + __expf(-acc));
}

// =====================================================================
// Kernel B v3: X_g = x @ w_g^T, f16 MFMA, double-buffered LDS,
// ONE lgkm-only barrier per kc; next-kc global loads stay in flight
// across the barrier (no vmcnt drain).
// =====================================================================
__global__ __launch_bounds__(256, 2) void kproj_kernel(
    const float* __restrict__ x, const float* __restrict__ w_r,
    const float* __restrict__ w_z, const float* __restrict__ w_h,
    _Float16* __restrict__ wsX) {
  const int g = blockIdx.y;
  const float* w = (g == 0) ? w_r : (g == 1) ? w_z : w_h;
  const int r0 = blockIdx.x * 128;

  __shared__ __align__(16) _Float16 Ah[2][128 * 40];
  __shared__ __align__(16) _Float16 Bh[2][128 * 40];

  const int tid = threadIdx.x;
  const int lane = tid & 63;
  const int wv = tid >> 6;
  const int wrow = (wv >> 1) * 64;
  const int wcol = (wv & 1) * 64;
  const int fr = lane & 15;
  const int fg = lane >> 4;

  const int srow = tid >> 1;          // 0..127
  const int kseg = (tid & 1) * 16;    // 0 or 16
  const float4* xrow = (const float4*)(x + (size_t)(r0 + srow) * NIN + kseg);
  const float4* wrp  = (const float4*)(w + (size_t)srow * NIN + kseg);

  f32x4 acc[4][4];
#pragma unroll
  for (int m = 0; m < 4; ++m)
#pragma unroll
    for (int n = 0; n < 4; ++n) acc[m][n] = (f32x4){0.f, 0.f, 0.f, 0.f};

  // preload kc=0 (16 floats of x, 16 of w per thread)
  float4 xg[4], wg[4];
#pragma unroll
  for (int i = 0; i < 4; ++i) { xg[i] = xrow[i]; wg[i] = wrp[i]; }

  for (int kc = 0; kc < 8; ++kc) {
    const int buf = kc & 1;
    // ---- cvt + stage current (2 b128 writes per tile per thread) ----
    {
      f16x8 h0, h1;
      h0[0]=(_Float16)xg[0].x; h0[1]=(_Float16)xg[0].y; h0[2]=(_Float16)xg[0].z; h0[3]=(_Float16)xg[0].w;
      h0[4]=(_Float16)xg[1].x; h0[5]=(_Float16)xg[1].y; h0[6]=(_Float16)xg[1].z; h0[7]=(_Float16)xg[1].w;
      h1[0]=(_Float16)xg[2].x; h1[1]=(_Float16)xg[2].y; h1[2]=(_Float16)xg[2].z; h1[3]=(_Float16)xg[2].w;
      h1[4]=(_Float16)xg[3].x; h1[5]=(_Float16)xg[3].y; h1[6]=(_Float16)xg[3].z; h1[7]=(_Float16)xg[3].w;
      *(f16x8*)&Ah[buf][srow * 40 + kseg]     = h0;
      *(f16x8*)&Ah[buf][srow * 40 + kseg + 8] = h1;
      f16x8 g0, g1;
      g0[0]=(_Float16)wg[0].x; g0[1]=(_Float16)wg[0].y; g0[2]=(_Float16)wg[0].z; g0[3]=(_Float16)wg[0].w;
      g0[4]=(_Float16)wg[1].x; g0[5]=(_Float16)wg[1].y; g0[6]=(_Float16)wg[1].z; g0[7]=(_Float16)wg[1].w;
      g1[0]=(_Float16)wg[2].x; g1[1]=(_Float16)wg[2].y; g1[2]=(_Float16)wg[2].z; g1[3]=(_Float16)wg[2].w;
      g1[4]=(_Float16)wg[3].x; g1[5]=(_Float16)wg[3].y; g1[6]=(_Float16)wg[3].z; g1[7]=(_Float16)wg[3].w;
      *(f16x8*)&Bh[buf][srow * 40 + kseg]     = g0;
      *(f16x8*)&Bh[buf][srow * 40 + kseg + 8] = g1;
    }
    // ---- issue next-kc loads; they stay in flight across the barrier ----
    if (kc < 7) {
#pragma unroll
      for (int i = 0; i < 4; ++i) {
        xg[i] = xrow[(kc + 1) * 8 + i];
        wg[i] = wrp[(kc + 1) * 8 + i];
      }
    }
    BAR_LDS();   // lgkm drain only — global loads NOT drained

    // ---- frags + MFMA from buf ----
    f16x8 a4[4], b4[4];
#pragma unroll
    for (int m = 0; m < 4; ++m) {
      a4[m] = *(const f16x8*)(&Ah[buf][(wrow + m * 16 + fr) * 40 + 8 * fg]);
      b4[m] = *(const f16x8*)(&Bh[buf][(wcol + m * 16 + fr) * 40 + 8 * fg]);
    }
#pragma unroll
    for (int m = 0; m < 4; ++m)
#pragma unroll
      for (int n = 0; n < 4; ++n)
        acc[m][n] = __builtin_amdgcn_mfma_f32_16x16x32_f16(a4[m], b4[n], acc[m][n], 0, 0, 0);
  }

#pragma unroll
  for (int m = 0; m < 4; ++m)
#pragma unroll
    for (int n = 0; n < 4; ++n)
#pragma unroll
      for (int r = 0; r < 4; ++r) {
        int row = r0 + wrow + m * 16 + fg * 4 + r;
        int col = wcol + n * 16 + fr;
        wsX[(size_t)g * BLD + (size_t)row * ND + col] = (_Float16)acc[m][n][r];
      }
}

// =====================================================================
// Kernel C v4 (revert to R4): 4-wave MFMA scan, raw s_barrier,
// pipelined (a, cor, ieff, hist-frag) state, async-chunked X.
// NOTE: per-wave live state must stay < ~200 VGPR (R5 lesson: 2-wave
// variant spilled and ran 2x slower).
// =====================================================================
__global__ __launch_bounds__(256, 1) void kscan_kernel(
    const float* __restrict__ u_r, const float* __restrict__ u_z,
    const float* __restrict__ u_h, const float* __restrict__ b_r,
    const float* __restrict__ b_z, const float* __restrict__ b_h,
    const int* __restrict__ cor, const _Float16* __restrict__ wsX,
    const float* __restrict__ wsA, float* __restrict__ out) {
  const int b = blockIdx.x;
  const int tid = threadIdx.x;
  const int lane = tid & 63;
  const int w = tid >> 6;        // wave id -> d range [32w, 32w+32)
  const int quad = lane >> 4;
  const int l16 = lane & 15;
  const int q8 = quad * 8;

  __shared__ __align__(16) _Float16 hist[(NL + 1) * NH];   // 32896 B
  __shared__ __align__(16) _Float16 Xl[2 * 3 * CH * ND];   // 24576 B
  __shared__ __align__(16) float hprev32[2][ND];           // 1024 B (parity)
  __shared__ __align__(16) _Float16 hprev16[2][NH];        // 256 B (parity)
  __shared__ float sA[NL];
  __shared__ int sCor[NL];

  // ---- B fragments: u_g[n][k] f16; n = 32w+16tt+l16, k = kk*32+q8+j ----
  f16x8 bf[3][2][4];
#pragma unroll
  for (int g = 0; g < 3; ++g) {
    const float* ug = (g == 0) ? u_r : (g == 1) ? u_z : u_h;
#pragma unroll
    for (int tt = 0; tt < 2; ++tt) {
      const float* base = ug + (size_t)(32 * w + 16 * tt + l16) * ND;
#pragma unroll
      for (int kk = 0; kk < 4; ++kk) {
        const float4* p = (const float4*)(base + kk * 32 + q8);
        float4 v0 = p[0], v1 = p[1];
        f16x8 f;
        f[0] = (_Float16)v0.x; f[1] = (_Float16)v0.y;
        f[2] = (_Float16)v0.z; f[3] = (_Float16)v0.w;
        f[4] = (_Float16)v1.x; f[5] = (_Float16)v1.y;
        f[6] = (_Float16)v1.z; f[7] = (_Float16)v1.w;
        bf[g][tt][kk] = f;
      }
    }
  }

  const size_t rowb = (size_t)b * NL;
  if (tid < ND) { hprev32[0][tid] = 0.f; }
  if (tid < NH) { hprev16[0][tid] = (_Float16)0.f; hist[tid] = (_Float16)0.f; }
  sA[tid] = wsA[rowb + tid];
  sCor[tid] = cor[rowb + tid];

  // ---- chunk 0 of X into Xl buf 0 (wave g loads gate g; 4x 1KB each) ----
  if (w < 3) {
    const _Float16* src = wsX + (size_t)w * BLD + rowb * ND + lane * 8;
    _Float16* dst = &Xl[w * (CH * ND)];
#pragma unroll
    for (int i = 0; i < 4; ++i)
      gload_lds16(src + i * 512, dst + i * 512);
  }

  const bool owner = (quad == 0);
  const int dd[2] = {32 * w + l16, 32 * w + l16 + 16};
  float bb[3][2] = {{0.f, 0.f}, {0.f, 0.f}, {0.f, 0.f}};
  if (owner) {
    bb[0][0] = b_r[dd[0]]; bb[0][1] = b_r[dd[1]];
    bb[1][0] = b_z[dd[0]]; bb[1][1] = b_z[dd[1]];
    bb[2][0] = b_h[dd[0]]; bb[2][1] = b_h[dd[1]];
  }
  __syncthreads();   // full drain once: chunk-0 loads + LDS init visible

  // ---- pipelined per-step state ----
  float a_c = sA[0];
  int c0 = sCor[0];
  int ieff_c = (c0 == 0) ? 0 : c0;
  bool pf_c = true;
  f16x8 af2 = *(const f16x8*)&hist[ieff_c * NH + q8];
  f16x8 af3 = *(const f16x8*)&hist[ieff_c * NH + 32 + q8];

  for (int t = 0; t < NL; ++t) {
    const int par = t & 1;
    const float a = a_c;
    const float oma = 1.f - a;
    const int ieff = ieff_c;
    const int cur = (t >> 4) & 1;
    const int tin = t & 15;

    // ---- issue next X chunk (once per 16 steps) ----
    if ((t & 15) == 0 && t + CH < NL && w < 3) {
      const _Float16* src = wsX + (size_t)w * BLD + (rowb + t + CH) * ND + lane * 8;
      _Float16* dst = &Xl[(cur ^ 1) * (3 * CH * ND) + w * (CH * ND)];
#pragma unroll
      for (int i = 0; i < 4; ++i)
        gload_lds16(src + i * 512, dst + i * 512);
    }

    // ---- hist frags: prefetched last step unless row was written last step
    if (!pf_c) {
      af2 = *(const f16x8*)&hist[ieff * NH + q8];
      af3 = *(const f16x8*)&hist[ieff * NH + 32 + q8];
    }
    f16x8 af0 = *(const f16x8*)&hprev16[par][q8];
    f16x8 af1 = *(const f16x8*)&hprev16[par][32 + q8];

    // ---- X + md reads for this step (owner lanes; from LDS) ----
    float xv[3][2], md[2];
    if (owner) {
      const _Float16* xp = &Xl[cur * (3 * CH * ND) + tin * ND];
#pragma unroll
      for (int g = 0; g < 3; ++g) {
        xv[g][0] = (float)xp[g * (CH * ND) + dd[0]];
        xv[g][1] = (float)xp[g * (CH * ND) + dd[1]];
      }
      if (w < 2) {
        md[0] = a * hprev32[par][dd[0]];
        md[1] = a * hprev32[par][dd[1]];
      } else if (ieff == t) {
        md[0] = oma * hprev32[par][dd[0]];
        md[1] = oma * hprev32[par][dd[1]];
      } else {
        md[0] = oma * (float)hist[ieff * NH + (dd[0] - NH)];
        md[1] = oma * (float)hist[ieff * NH + (dd[1] - NH)];
      }
    }

    // ---- MFMA: lo (k<64) and hi (k>=64) accumulators ----
    f32x4 accL[3][2], accH[3][2];
#pragma unroll
    for (int g = 0; g < 3; ++g)
#pragma unroll
      for (int tt = 0; tt < 2; ++tt) {
        accL[g][tt] = (f32x4){0.f, 0.f, 0.f, 0.f};
        accH[g][tt] = (f32x4){0.f, 0.f, 0.f, 0.f};
      }
#pragma unroll
    for (int g = 0; g < 3; ++g)
#pragma unroll
      for (int tt = 0; tt < 2; ++tt) {
        accL[g][tt] = __builtin_amdgcn_mfma_f32_16x16x32_f16(af0, bf[g][tt][0], accL[g][tt], 0, 0, 0);
        accH[g][tt] = __builtin_amdgcn_mfma_f32_16x16x32_f16(af2, bf[g][tt][2], accH[g][tt], 0, 0, 0);
        accL[g][tt] = __builtin_amdgcn_mfma_f32_16x16x32_f16(af1, bf[g][tt][1], accL[g][tt], 0, 0, 0);
        accH[g][tt] = __builtin_amdgcn_mfma_f32_16x16x32_f16(af3, bf[g][tt][3], accH[g][tt], 0, 0, 0);
      }

    // ---- prefetch step-(t+1) state (overlaps MFMA/epilogue) ----
    const int tn = (t < NL - 1) ? t + 1 : t;
    float a_n = sA[tn];
    int c_n = sCor[tn];
    int ieff_n = (c_n == 0) ? tn : c_n;
    bool pf_n = (ieff_n <= t);         // row stable during this step?
    f16x8 af2n, af3n;
    if (pf_n) {
      af2n = *(const f16x8*)&hist[ieff_n * NH + q8];
      af3n = *(const f16x8*)&hist[ieff_n * NH + 32 + q8];
    }

    // ---- epilogue (owner lanes; row 0 of C => quad 0, reg 0) ----
    if (owner) {
#pragma unroll
      for (int tt = 0; tt < 2; ++tt) {
        float dr = a * accL[0][tt][0] + oma * accH[0][tt][0];
        float dz = a * accL[1][tt][0] + oma * accH[1][tt][0];
        float dh = a * accL[2][tt][0] + oma * accH[2][tt][0];
        float rr = 1.f / (1.f + __expf(-(xv[0][tt] + bb[0][tt] + dr)));
        float zz = 1.f / (1.f + __expf(-(xv[1][tt] + bb[1][tt] + dz)));
        float e2 = __expf(2.f * (xv[2][tt] + bb[2][tt] + rr * dh));
        float hh = (e2 - 1.f) / (e2 + 1.f);
        float h = (1.f - zz) * md[tt] + zz * hh;
        int d = dd[tt];
        out[(rowb + t) * ND + d] = h;      // never drained per-step
        hprev32[par ^ 1][d] = h;
        if (d < NH) hprev16[par ^ 1][d] = (_Float16)h;
        else        hist[(t + 1) * NH + (d - NH)] = (_Float16)h;
      }
    }

    // ---- barrier: LDS drain only; vmcnt(0) only at chunk boundaries ----
    if ((t & 15) == 15) WAIT_VM0();
    BAR_LDS();

    a_c = a_n; ieff_c = ieff_n; pf_c = pf_n;
    if (pf_n) { af2 = af2n; af3 = af3n; }
  }
}

// =====================================================================
extern "C" void kernel_launch(void* const* d_in, const int* in_sizes, int n_in,
                              void* d_out, int out_size, void* d_ws, size_t ws_size,
                              hipStream_t stream) {
  (void)in_sizes; (void)n_in; (void)out_size; (void)ws_size;
  const float* x    = (const float*)d_in[0];
  const int*   cor  = (const int*)d_in[1];
  const float* w_r  = (const float*)d_in[2];
  const float* b_r  = (const float*)d_in[3];
  const float* u_r  = (const float*)d_in[4];
  const float* w_z  = (const float*)d_in[5];
  const float* b_z  = (const float*)d_in[6];
  const float* u_z  = (const float*)d_in[7];
  const float* w_h  = (const float*)d_in[8];
  const float* b_h  = (const float*)d_in[9];
  const float* u_h  = (const float*)d_in[10];
  const float* k1k2 = (const float*)d_in[11];

  _Float16* wsX = (_Float16*)d_ws;                       // 3*BL*ND f16 = 48 MB
  float* wsA = (float*)((char*)d_ws + 3 * BLD * 2);      // BL f32 = 256 KB

  ka_kernel<<<dim3(BL / 16), dim3(256), 0, stream>>>(x, k1k2, wsA);
  kproj_kernel<<<dim3(BL / 128, 3), dim3(256), 0, stream>>>(x, w_r, w_z, w_h, wsX);
  kscan_kernel<<<dim3(NB), dim3(256), 0, stream>>>(u_r, u_z, u_h, b_r, b_z, b_h,
                                                   cor, wsX, wsA, (float*)d_out);
}

// Round 7
// 371.146 us; speedup vs baseline: 1.6311x; 1.0321x over previous
//
#include <hip/hip_runtime.h>

typedef unsigned short ushort_t;
typedef float f32x4 __attribute__((ext_vector_type(4)));
typedef _Float16 f16x8 __attribute__((ext_vector_type(8)));
typedef _Float16 f16x4 __attribute__((ext_vector_type(4)));

#define NB 256
#define NL 256
#define NIN 256
#define ND 128
#define NH 64
#define BL (NB * NL)                 // 65536 rows
#define BLD ((size_t)BL * ND)        // 8,388,608 elements per gate
#define CH 16                        // X-staging chunk (steps)

// raw barrier: LDS-only drain (no vmcnt!) — global ops float across it
#define BAR_LDS() asm volatile("s_waitcnt lgkmcnt(0)\n\ts_barrier" ::: "memory")
#define WAIT_VM0() asm volatile("s_waitcnt vmcnt(0)" ::: "memory")

__device__ __forceinline__ void gload_lds16(const _Float16* gp, _Float16* lp) {
  __builtin_amdgcn_global_load_lds(
      (const __attribute__((address_space(1))) void*)gp,
      (__attribute__((address_space(3))) void*)lp, 16, 0, 0);
}

// =====================================================================
// Kernel W: pack w_r|w_z|w_h (f32 [128][256]) into f16 fragment order:
// wpk[((nt*8 + kc)*64 + lane)*8 + j] = w_gate[(nt&7)*16 + (lane&15)]
//                                       [kc*32 + (lane>>4)*8 + j]
// nt 0..7 -> w_r, 8..15 -> w_z, 16..23 -> w_h. 192 KB total, L2-resident.
// =====================================================================
__global__ void kwpack_kernel(const float* __restrict__ w_r,
                              const float* __restrict__ w_z,
                              const float* __restrict__ w_h,
                              _Float16* __restrict__ wpk) {
  const int lane = threadIdx.x;        // 0..63
  const int nt = blockIdx.x;           // 0..23
  const int kc = blockIdx.y;           // 0..7
  const float* wg = (nt < 8) ? w_r : (nt < 16) ? w_z : w_h;
  const int col = (nt & 7) * 16 + (lane & 15);
  const int k0 = kc * 32 + (lane >> 4) * 8;
  const float4* p = (const float4*)(wg + (size_t)col * NIN + k0);
  float4 v0 = p[0], v1 = p[1];
  f16x8 f;
  f[0] = (_Float16)v0.x; f[1] = (_Float16)v0.y;
  f[2] = (_Float16)v0.z; f[3] = (_Float16)v0.w;
  f[4] = (_Float16)v1.x; f[5] = (_Float16)v1.y;
  f[6] = (_Float16)v1.z; f[7] = (_Float16)v1.w;
  *(f16x8*)&wpk[(((size_t)nt * 8 + kc) * 64 + lane) * 8] = f;
}

// =====================================================================
// Kernel B v4 (fused): per 64-row tile, reads x ONCE, computes all 3
// gate projections (B streamed from wpk/L2 into registers, no w staging)
// AND the ka sigmoid inline from the fp32 x registers.
// 1024 blocks x 256 threads; wave w owns nt = 6w..6w+5 (N=384 concat).
// =====================================================================
__global__ __launch_bounds__(256, 2) void kproj_kernel(
    const float* __restrict__ x, const _Float16* __restrict__ wpk,
    const float* __restrict__ k1k2, _Float16* __restrict__ wsX,
    float* __restrict__ wsA) {
  const int r0 = blockIdx.x * 64;

  __shared__ __align__(16) _Float16 Ah[2][64 * 40];   // 10240 B
  __shared__ float k12[NIN];                          // 1024 B

  const int tid = threadIdx.x;
  const int lane = tid & 63;
  const int w = tid >> 6;
  const int l16 = lane & 15;
  const int q8 = (lane >> 4) * 8;

  k12[tid] = k1k2[tid] - k1k2[NIN + tid];

  const int srow = tid >> 2;          // 0..63
  const int seg = tid & 3;            // 8-float segment within 32-float kc
  const float4* xrow4 = (const float4*)(x + (size_t)(r0 + srow) * NIN + seg * 8);

  f32x4 acc[6][4];                    // [n-tile][m-tile]
#pragma unroll
  for (int i = 0; i < 6; ++i)
#pragma unroll
    for (int mt = 0; mt < 4; ++mt) acc[i][mt] = (f32x4){0.f, 0.f, 0.f, 0.f};

  // preload kc=0: x regs + B frags
  float4 xa = xrow4[0], xb = xrow4[1];
  f16x8 bcur[6], bnxt[6];
#pragma unroll
  for (int i = 0; i < 6; ++i)
    bcur[i] = *(const f16x8*)&wpk[(((size_t)(6 * w + i) * 8 + 0) * 64 + lane) * 8];

  float adot = 0.f;
  __syncthreads();                    // k12 visible

  for (int kc = 0; kc < 8; ++kc) {
    const int buf = kc & 1;
    // ---- ka partial (fp32, pre-truncation) ----
    {
      const float4* kk = (const float4*)&k12[kc * 32 + seg * 8];
      float4 k0 = kk[0], k1 = kk[1];
      adot += xa.x * k0.x + xa.y * k0.y + xa.z * k0.z + xa.w * k0.w +
              xb.x * k1.x + xb.y * k1.y + xb.z * k1.z + xb.w * k1.w;
    }
    // ---- cvt + stage x chunk ----
    {
      f16x8 h;
      h[0] = (_Float16)xa.x; h[1] = (_Float16)xa.y;
      h[2] = (_Float16)xa.z; h[3] = (_Float16)xa.w;
      h[4] = (_Float16)xb.x; h[5] = (_Float16)xb.y;
      h[6] = (_Float16)xb.z; h[7] = (_Float16)xb.w;
      *(f16x8*)&Ah[buf][srow * 40 + seg * 8] = h;
    }
    // ---- issue next-kc loads (x + B); in flight across the barrier ----
    if (kc < 7) {
      xa = xrow4[(kc + 1) * 8];
      xb = xrow4[(kc + 1) * 8 + 1];
#pragma unroll
      for (int i = 0; i < 6; ++i)
        bnxt[i] = *(const f16x8*)&wpk[(((size_t)(6 * w + i) * 8 + (kc + 1)) * 64 + lane) * 8];
    }
    BAR_LDS();   // lgkm drain only — global loads NOT drained

    // ---- A frags + MFMA ----
    f16x8 af[4];
#pragma unroll
    for (int mt = 0; mt < 4; ++mt)
      af[mt] = *(const f16x8*)&Ah[buf][(mt * 16 + l16) * 40 + q8];
#pragma unroll
    for (int i = 0; i < 6; ++i)
#pragma unroll
      for (int mt = 0; mt < 4; ++mt)
        acc[i][mt] = __builtin_amdgcn_mfma_f32_16x16x32_f16(af[mt], bcur[i], acc[i][mt], 0, 0, 0);
#pragma unroll
    for (int i = 0; i < 6; ++i) bcur[i] = bnxt[i];
  }

  // ---- ka reduce + store (lanes tid%4==0) ----
  adot += __shfl_xor(adot, 1);
  adot += __shfl_xor(adot, 2);
  if ((tid & 3) == 0) wsA[r0 + srow] = 1.f / (1.f + __expf(-adot));

  // ---- epilogue: C layout col=l16, row=(lane>>4)*4+r ----
#pragma unroll
  for (int i = 0; i < 6; ++i) {
    const int nt = 6 * w + i;
    const int g = nt >> 3;
    const int col = (nt & 7) * 16 + l16;
    _Float16* base = wsX + (size_t)g * BLD + col;
#pragma unroll
    for (int mt = 0; mt < 4; ++mt)
#pragma unroll
      for (int r = 0; r < 4; ++r) {
        int row = r0 + mt * 16 + (q8 >> 1) + r;   // (lane>>4)*4 + r
        base[(size_t)row * ND] = (_Float16)acc[i][mt][r];
      }
  }
}

// =====================================================================
// Kernel C v4.1: 4-wave MFMA scan (R4/R6 structure, proven 240 us).
// Change: per-chunk vmcnt(0) moved BEFORE the epilogue stores, so it
// only waits 15-step-old chunk loads (~free), never this step's stores.
// NOTE: per-wave live state must stay < ~200 VGPR (R5 spill lesson).
// =====================================================================
__global__ __launch_bounds__(256, 1) void kscan_kernel(
    const float* __restrict__ u_r, const float* __restrict__ u_z,
    const float* __restrict__ u_h, const float* __restrict__ b_r,
    const float* __restrict__ b_z, const float* __restrict__ b_h,
    const int* __restrict__ cor, const _Float16* __restrict__ wsX,
    const float* __restrict__ wsA, float* __restrict__ out) {
  const int b = blockIdx.x;
  const int tid = threadIdx.x;
  const int lane = tid & 63;
  const int w = tid >> 6;        // wave id -> d range [32w, 32w+32)
  const int quad = lane >> 4;
  const int l16 = lane & 15;
  const int q8 = quad * 8;

  __shared__ __align__(16) _Float16 hist[(NL + 1) * NH];   // 32896 B
  __shared__ __align__(16) _Float16 Xl[2 * 3 * CH * ND];   // 24576 B
  __shared__ __align__(16) float hprev32[2][ND];           // 1024 B (parity)
  __shared__ __align__(16) _Float16 hprev16[2][NH];        // 256 B (parity)
  __shared__ float sA[NL];
  __shared__ int sCor[NL];

  // ---- B fragments: u_g[n][k] f16; n = 32w+16tt+l16, k = kk*32+q8+j ----
  f16x8 bf[3][2][4];
#pragma unroll
  for (int g = 0; g < 3; ++g) {
    const float* ug = (g == 0) ? u_r : (g == 1) ? u_z : u_h;
#pragma unroll
    for (int tt = 0; tt < 2; ++tt) {
      const float* base = ug + (size_t)(32 * w + 16 * tt + l16) * ND;
#pragma unroll
      for (int kk = 0; kk < 4; ++kk) {
        const float4* p = (const float4*)(base + kk * 32 + q8);
        float4 v0 = p[0], v1 = p[1];
        f16x8 f;
        f[0] = (_Float16)v0.x; f[1] = (_Float16)v0.y;
        f[2] = (_Float16)v0.z; f[3] = (_Float16)v0.w;
        f[4] = (_Float16)v1.x; f[5] = (_Float16)v1.y;
        f[6] = (_Float16)v1.z; f[7] = (_Float16)v1.w;
        bf[g][tt][kk] = f;
      }
    }
  }

  const size_t rowb = (size_t)b * NL;
  if (tid < ND) { hprev32[0][tid] = 0.f; }
  if (tid < NH) { hprev16[0][tid] = (_Float16)0.f; hist[tid] = (_Float16)0.f; }
  sA[tid] = wsA[rowb + tid];
  sCor[tid] = cor[rowb + tid];

  // ---- chunk 0 of X into Xl buf 0 (wave g loads gate g; 4x 1KB each) ----
  if (w < 3) {
    const _Float16* src = wsX + (size_t)w * BLD + rowb * ND + lane * 8;
    _Float16* dst = &Xl[w * (CH * ND)];
#pragma unroll
    for (int i = 0; i < 4; ++i)
      gload_lds16(src + i * 512, dst + i * 512);
  }

  const bool owner = (quad == 0);
  const int dd[2] = {32 * w + l16, 32 * w + l16 + 16};
  float bb[3][2] = {{0.f, 0.f}, {0.f, 0.f}, {0.f, 0.f}};
  if (owner) {
    bb[0][0] = b_r[dd[0]]; bb[0][1] = b_r[dd[1]];
    bb[1][0] = b_z[dd[0]]; bb[1][1] = b_z[dd[1]];
    bb[2][0] = b_h[dd[0]]; bb[2][1] = b_h[dd[1]];
  }
  __syncthreads();   // full drain once: chunk-0 loads + LDS init visible

  // ---- pipelined per-step state ----
  float a_c = sA[0];
  int c0 = sCor[0];
  int ieff_c = (c0 == 0) ? 0 : c0;
  bool pf_c = true;
  f16x8 af2 = *(const f16x8*)&hist[ieff_c * NH + q8];
  f16x8 af3 = *(const f16x8*)&hist[ieff_c * NH + 32 + q8];

  for (int t = 0; t < NL; ++t) {
    const int par = t & 1;
    const float a = a_c;
    const float oma = 1.f - a;
    const int ieff = ieff_c;
    const int cur = (t >> 4) & 1;
    const int tin = t & 15;

    // ---- issue next X chunk (once per 16 steps) ----
    if (tin == 0 && t + CH < NL && w < 3) {
      const _Float16* src = wsX + (size_t)w * BLD + (rowb + t + CH) * ND + lane * 8;
      _Float16* dst = &Xl[(cur ^ 1) * (3 * CH * ND) + w * (CH * ND)];
#pragma unroll
      for (int i = 0; i < 4; ++i)
        gload_lds16(src + i * 512, dst + i * 512);
    }

    // ---- hist frags: prefetched last step unless row was written last step
    if (!pf_c) {
      af2 = *(const f16x8*)&hist[ieff * NH + q8];
      af3 = *(const f16x8*)&hist[ieff * NH + 32 + q8];
    }
    f16x8 af0 = *(const f16x8*)&hprev16[par][q8];
    f16x8 af1 = *(const f16x8*)&hprev16[par][32 + q8];

    // ---- X + md reads for this step (owner lanes; from LDS) ----
    float xv[3][2], md[2];
    if (owner) {
      const _Float16* xp = &Xl[cur * (3 * CH * ND) + tin * ND];
#pragma unroll
      for (int g = 0; g < 3; ++g) {
        xv[g][0] = (float)xp[g * (CH * ND) + dd[0]];
        xv[g][1] = (float)xp[g * (CH * ND) + dd[1]];
      }
      if (w < 2) {
        md[0] = a * hprev32[par][dd[0]];
        md[1] = a * hprev32[par][dd[1]];
      } else if (ieff == t) {
        md[0] = oma * hprev32[par][dd[0]];
        md[1] = oma * hprev32[par][dd[1]];
      } else {
        md[0] = oma * (float)hist[ieff * NH + (dd[0] - NH)];
        md[1] = oma * (float)hist[ieff * NH + (dd[1] - NH)];
      }
    }

    // ---- MFMA: lo (k<64) and hi (k>=64) accumulators ----
    f32x4 accL[3][2], accH[3][2];
#pragma unroll
    for (int g = 0; g < 3; ++g)
#pragma unroll
      for (int tt = 0; tt < 2; ++tt) {
        accL[g][tt] = (f32x4){0.f, 0.f, 0.f, 0.f};
        accH[g][tt] = (f32x4){0.f, 0.f, 0.f, 0.f};
      }
#pragma unroll
    for (int g = 0; g < 3; ++g)
#pragma unroll
      for (int tt = 0; tt < 2; ++tt) {
        accL[g][tt] = __builtin_amdgcn_mfma_f32_16x16x32_f16(af0, bf[g][tt][0], accL[g][tt], 0, 0, 0);
        accH[g][tt] = __builtin_amdgcn_mfma_f32_16x16x32_f16(af2, bf[g][tt][2], accH[g][tt], 0, 0, 0);
        accL[g][tt] = __builtin_amdgcn_mfma_f32_16x16x32_f16(af1, bf[g][tt][1], accL[g][tt], 0, 0, 0);
        accH[g][tt] = __builtin_amdgcn_mfma_f32_16x16x32_f16(af3, bf[g][tt][3], accH[g][tt], 0, 0, 0);
      }

    // ---- prefetch step-(t+1) state (overlaps MFMA/epilogue) ----
    const int tn = (t < NL - 1) ? t + 1 : t;
    float a_n = sA[tn];
    int c_n = sCor[tn];
    int ieff_n = (c_n == 0) ? tn : c_n;
    bool pf_n = (ieff_n <= t);         // row stable during this step?
    f16x8 af2n, af3n;
    if (pf_n) {
      af2n = *(const f16x8*)&hist[ieff_n * NH + q8];
      af3n = *(const f16x8*)&hist[ieff_n * NH + 32 + q8];
    }

    // ---- drain chunk loads BEFORE this step's stores are issued ----
    if (tin == 15) WAIT_VM0();   // waits only 15-step-old loads (~free)

    // ---- epilogue (owner lanes; row 0 of C => quad 0, reg 0) ----
    if (owner) {
#pragma unroll
      for (int tt = 0; tt < 2; ++tt) {
        float dr = a * accL[0][tt][0] + oma * accH[0][tt][0];
        float dz = a * accL[1][tt][0] + oma * accH[1][tt][0];
        float dh = a * accL[2][tt][0] + oma * accH[2][tt][0];
        float rr = 1.f / (1.f + __expf(-(xv[0][tt] + bb[0][tt] + dr)));
        float zz = 1.f / (1.f + __expf(-(xv[1][tt] + bb[1][tt] + dz)));
        float e2 = __expf(2.f * (xv[2][tt] + bb[2][tt] + rr * dh));
        float hh = (e2 - 1.f) / (e2 + 1.f);
        float h = (1.f - zz) * md[tt] + zz * hh;
        int d = dd[tt];
        out[(rowb + t) * ND + d] = h;      // never drained per-step
        hprev32[par ^ 1][d] = h;
        if (d < NH) hprev16[par ^ 1][d] = (_Float16)h;
        else        hist[(t + 1) * NH + (d - NH)] = (_Float16)h;
      }
    }

    BAR_LDS();   // LDS drain only

    a_c = a_n; ieff_c = ieff_n; pf_c = pf_n;
    if (pf_n) { af2 = af2n; af3 = af3n; }
  }
}

// =====================================================================
extern "C" void kernel_launch(void* const* d_in, const int* in_sizes, int n_in,
                              void* d_out, int out_size, void* d_ws, size_t ws_size,
                              hipStream_t stream) {
  (void)in_sizes; (void)n_in; (void)out_size; (void)ws_size;
  const float* x    = (const float*)d_in[0];
  const int*   cor  = (const int*)d_in[1];
  const float* w_r  = (const float*)d_in[2];
  const float* b_r  = (const float*)d_in[3];
  const float* u_r  = (const float*)d_in[4];
  const float* w_z  = (const float*)d_in[5];
  const float* b_z  = (const float*)d_in[6];
  const float* u_z  = (const float*)d_in[7];
  const float* w_h  = (const float*)d_in[8];
  const float* b_h  = (const float*)d_in[9];
  const float* u_h  = (const float*)d_in[10];
  const float* k1k2 = (const float*)d_in[11];

  _Float16* wsX = (_Float16*)d_ws;                            // 48 MB
  float* wsA = (float*)((char*)d_ws + 3 * BLD * 2);           // 256 KB
  _Float16* wpk = (_Float16*)((char*)d_ws + 3 * BLD * 2 + BL * 4);  // 192 KB

  kwpack_kernel<<<dim3(24, 8), dim3(64), 0, stream>>>(w_r, w_z, w_h, wpk);
  kproj_kernel<<<dim3(BL / 64), dim3(256), 0, stream>>>(x, wpk, k1k2, wsX, wsA);
  kscan_kernel<<<dim3(NB), dim3(256), 0, stream>>>(u_r, u_z, u_h, b_r, b_z, b_h,
                                                   cor, wsX, wsA, (float*)d_out);
}